// Round 2
// baseline (325.024 us; speedup 1.0000x reference)
//
#include <hip/hip_runtime.h>
#include <math.h>

#define N_NODES 100000
#define N_EDGES 1600000
#define F0 32
#define F1 16
#define F2 8
#define NCLS 6
#define NGRAPH 64

#define SCAN_B 512
#define NBLK ((N_NODES + SCAN_B - 1) / SCAN_B)   // 196

// ---- fused: xw1 = x @ W1a (per node)  +  in-degree histogram (per edge) ----
// Projecting 32->16 BEFORE aggregation (linearity) halves gather traffic.
__global__ __launch_bounds__(256) void xform_hist_k(
    const float* __restrict__ x, const float* __restrict__ W1a,
    float* __restrict__ xw1, const int* __restrict__ ei, int* __restrict__ cnt) {
    __shared__ float sW[F0 * F1];
    int t = threadIdx.x;
    int gid = blockIdx.x * blockDim.x + t;
    if (gid < N_EDGES) atomicAdd(&cnt[ei[N_EDGES + gid]], 1);   // int atomic, cheap
    for (int i = t; i < F0 * F1; i += blockDim.x) sW[i] = W1a[i];
    __syncthreads();
    if (gid >= N_NODES) return;
    const float4* xp = reinterpret_cast<const float4*>(x) + gid * (F0 / 4);
    float xi[F0];
#pragma unroll
    for (int q = 0; q < F0 / 4; q++) {
        float4 v = xp[q];
        xi[4 * q + 0] = v.x; xi[4 * q + 1] = v.y;
        xi[4 * q + 2] = v.z; xi[4 * q + 3] = v.w;
    }
    float o[F1];
#pragma unroll
    for (int j = 0; j < F1; j++) {
        float s = 0.0f;
#pragma unroll
        for (int k = 0; k < F0; k++) s += xi[k] * sW[k * F1 + j];
        o[j] = s;
    }
    float4* op = reinterpret_cast<float4*>(xw1) + gid * (F1 / 4);
#pragma unroll
    for (int q = 0; q < F1 / 4; q++)
        op[q] = make_float4(o[4 * q + 0], o[4 * q + 1], o[4 * q + 2], o[4 * q + 3]);
}

// ---- per-block inclusive scan of cnt -> rowptr[i+1], block sums -> bsum ----
__global__ __launch_bounds__(SCAN_B) void scanB_k(
    const int* __restrict__ cnt, int* __restrict__ rowptr, int* __restrict__ bsum) {
    __shared__ int buf[2][SCAN_B];
    int t = threadIdx.x;
    int i = blockIdx.x * SCAN_B + t;
    int v = (i < N_NODES) ? cnt[i] : 0;
    int cur = 0;
    buf[0][t] = v;
    __syncthreads();
    for (int off = 1; off < SCAN_B; off <<= 1) {
        int xv = buf[cur][t];
        if (t >= off) xv += buf[cur][t - off];
        buf[cur ^ 1][t] = xv;
        cur ^= 1;
        __syncthreads();
    }
    int inc = buf[cur][t];
    if (i < N_NODES) rowptr[i + 1] = inc;
    if (t == SCAN_B - 1) bsum[blockIdx.x] = inc;
}

// ---- every block redundantly scans bsum (196 vals), adds its offset ----
__global__ __launch_bounds__(SCAN_B) void scanD_k(
    int* __restrict__ rowptr, const int* __restrict__ bsum) {
    __shared__ int buf[2][SCAN_B];
    int t = threadIdx.x;
    int v = (t < NBLK) ? bsum[t] : 0;
    int cur = 0;
    buf[0][t] = v;
    __syncthreads();
    for (int off = 1; off < SCAN_B; off <<= 1) {
        int xv = buf[cur][t];
        if (t >= off) xv += buf[cur][t - off];
        buf[cur ^ 1][t] = xv;
        cur ^= 1;
        __syncthreads();
    }
    int boff = buf[cur][blockIdx.x] - bsum[blockIdx.x];   // exclusive offset
    int i = blockIdx.x * SCAN_B + t;
    if (i < N_NODES) rowptr[i + 1] += boff;
    if (i == 0) rowptr[0] = 0;
}

// ---- fill CSR: slot via atomicSub on cnt (counts -> 0), store src ----
__global__ __launch_bounds__(256) void fill_k(
    const int* __restrict__ ei, const int* __restrict__ rowptr,
    int* __restrict__ cnt, int* __restrict__ srcs) {
    int e = blockIdx.x * blockDim.x + threadIdx.x;
    if (e >= N_EDGES) return;
    int s = ei[e];
    int d = ei[N_EDGES + e];
    int r = atomicSub(&cnt[d], 1) - 1;
    srcs[rowptr[d] + r] = s;
}

#define ACC16(P) { float4 q0 = (P)[0], q1 = (P)[1], q2 = (P)[2], q3 = (P)[3]; \
    acc[0] += q0.x;  acc[1] += q0.y;  acc[2]  += q0.z;  acc[3]  += q0.w;      \
    acc[4] += q1.x;  acc[5] += q1.y;  acc[6]  += q1.z;  acc[7]  += q1.w;      \
    acc[8] += q2.x;  acc[9] += q2.y;  acc[10] += q2.z;  acc[11] += q2.w;      \
    acc[12] += q3.x; acc[13] += q3.y; acc[14] += q3.z;  acc[15] += q3.w; }

// ---- layer 1: gather-sum (register acc) + MLP1 + project with W2a ----
__global__ __launch_bounds__(256) void gin1_k(
    const float* __restrict__ xw1, const int* __restrict__ rowptr,
    const int* __restrict__ srcs, const float* __restrict__ b1a,
    const float* __restrict__ W1b, const float* __restrict__ b1b,
    const float* __restrict__ W2a, float* __restrict__ h1w) {
    __shared__ float sW1b[F1 * F1];
    __shared__ float sW2a[F1 * F2];
    __shared__ float sb1a[F1];
    __shared__ float sb1b[F1];
    int t = threadIdx.x;
    for (int i = t; i < F1 * F1; i += blockDim.x) sW1b[i] = W1b[i];
    for (int i = t; i < F1 * F2; i += blockDim.x) sW2a[i] = W2a[i];
    if (t < F1) { sb1a[t] = b1a[t]; sb1b[t] = b1b[t]; }
    __syncthreads();

    int n = blockIdx.x * blockDim.x + t;
    if (n >= N_NODES) return;

    float acc[F1];
#pragma unroll
    for (int k = 0; k < F1; k++) acc[k] = 0.0f;

    const float4* X = reinterpret_cast<const float4*>(xw1);
    int e = rowptr[n];
    int end = rowptr[n + 1];
    for (; e + 2 <= end; e += 2) {          // unroll-2 for load ILP
        int s0 = srcs[e], s1 = srcs[e + 1];
        const float4* p0 = X + s0 * 4;
        const float4* p1 = X + s1 * 4;
        ACC16(p0);
        ACC16(p1);
    }
    if (e < end) {
        const float4* p0 = X + srcs[e] * 4;
        ACC16(p0);
    }
    {   // self term: x_n @ W1a
        const float4* pn = X + n * 4;
        ACC16(pn);
    }

    float u[F1];
#pragma unroll
    for (int k = 0; k < F1; k++) u[k] = fmaxf(acc[k] + sb1a[k], 0.0f);

    float h[F1];
#pragma unroll
    for (int j = 0; j < F1; j++) {
        float s = sb1b[j];
#pragma unroll
        for (int k = 0; k < F1; k++) s += u[k] * sW1b[k * F1 + j];
        h[j] = fmaxf(s, 0.0f);              // relu∘relu = relu
    }
    float o[F2];
#pragma unroll
    for (int j = 0; j < F2; j++) {
        float s = 0.0f;
#pragma unroll
        for (int k = 0; k < F1; k++) s += h[k] * sW2a[k * F2 + j];
        o[j] = s;
    }
    float4* hp = reinterpret_cast<float4*>(h1w) + n * 2;
    hp[0] = make_float4(o[0], o[1], o[2], o[3]);
    hp[1] = make_float4(o[4], o[5], o[6], o[7]);
}

#define ACC8(P) { float4 q0 = (P)[0], q1 = (P)[1];                        \
    acc[0] += q0.x; acc[1] += q0.y; acc[2] += q0.z; acc[3] += q0.w;       \
    acc[4] += q1.x; acc[5] += q1.y; acc[6] += q1.z; acc[7] += q1.w; }

// ---- layer 2: gather-sum + MLP2 + fused mean-pool accumulation ----
__global__ __launch_bounds__(256) void gin2pool_k(
    const float* __restrict__ h1w, const int* __restrict__ rowptr,
    const int* __restrict__ srcs, const float* __restrict__ b2a,
    const float* __restrict__ W2b, const float* __restrict__ b2b,
    const int* __restrict__ batch, float* __restrict__ gsum,
    float* __restrict__ gcnt) {
    __shared__ float sW2b[F2 * F2];
    __shared__ float sb2a[F2];
    __shared__ float sb2b[F2];
    __shared__ float ls[NGRAPH * F2];
    __shared__ float lc[NGRAPH];
    int t = threadIdx.x;
    for (int i = t; i < F2 * F2; i += blockDim.x) sW2b[i] = W2b[i];
    if (t < F2) { sb2a[t] = b2a[t]; sb2b[t] = b2b[t]; }
    for (int i = t; i < NGRAPH * F2; i += blockDim.x) ls[i] = 0.0f;
    if (t < NGRAPH) lc[t] = 0.0f;
    __syncthreads();

    int n = blockIdx.x * blockDim.x + t;
    if (n < N_NODES) {
        float acc[F2];
#pragma unroll
        for (int k = 0; k < F2; k++) acc[k] = 0.0f;

        const float4* H = reinterpret_cast<const float4*>(h1w);
        int e = rowptr[n];
        int end = rowptr[n + 1];
        for (; e + 2 <= end; e += 2) {
            int s0 = srcs[e], s1 = srcs[e + 1];
            const float4* p0 = H + s0 * 2;
            const float4* p1 = H + s1 * 2;
            ACC8(p0);
            ACC8(p1);
        }
        if (e < end) {
            const float4* p0 = H + srcs[e] * 2;
            ACC8(p0);
        }
        {   // self term
            const float4* pn = H + n * 2;
            ACC8(pn);
        }

        float u[F2];
#pragma unroll
        for (int k = 0; k < F2; k++) u[k] = fmaxf(acc[k] + sb2a[k], 0.0f);

        float v[F2];
#pragma unroll
        for (int j = 0; j < F2; j++) {
            float s = sb2b[j];
#pragma unroll
            for (int k = 0; k < F2; k++) s += u[k] * sW2b[k * F2 + j];
            v[j] = fmaxf(s, 0.0f);
        }
        int g = batch[n];
#pragma unroll
        for (int j = 0; j < F2; j++) atomicAdd(&ls[g * F2 + j], v[j]);
        atomicAdd(&lc[g], 1.0f);
    }
    __syncthreads();
    for (int i = t; i < NGRAPH * F2; i += blockDim.x)
        if (ls[i] != 0.0f) atomicAdd(&gsum[i], ls[i]);
    if (t < NGRAPH && lc[t] != 0.0f) atomicAdd(&gcnt[t], lc[t]);
}

// ---------------- final: pooled -> FC -> log_softmax ----------------
__global__ void final_k(const float* __restrict__ gsum,
                        const float* __restrict__ gcnt,
                        const float* __restrict__ Wfc, const float* __restrict__ bfc,
                        float* __restrict__ out) {
    int g = threadIdx.x;
    if (g >= NGRAPH) return;
    float cnt = fmaxf(gcnt[g], 1.0f);
    float p[F2];
#pragma unroll
    for (int f = 0; f < F2; f++) p[f] = gsum[g * F2 + f] / cnt;
    float l[NCLS];
#pragma unroll
    for (int c = 0; c < NCLS; c++) {
        float s = bfc[c];
#pragma unroll
        for (int f = 0; f < F2; f++) s += p[f] * Wfc[f * NCLS + c];
        l[c] = s;
    }
    float m = -INFINITY;
#pragma unroll
    for (int c = 0; c < NCLS; c++) m = fmaxf(m, l[c]);
    float s = 0.0f;
#pragma unroll
    for (int c = 0; c < NCLS; c++) s += expf(l[c] - m);
    float lse = m + logf(s);
#pragma unroll
    for (int c = 0; c < NCLS; c++) out[g * NCLS + c] = l[c] - lse;
}

extern "C" void kernel_launch(void* const* d_in, const int* in_sizes, int n_in,
                              void* d_out, int out_size, void* d_ws, size_t ws_size,
                              hipStream_t stream) {
    const float* x    = (const float*)d_in[0];
    const int*   ei   = (const int*)d_in[1];   // [2, N_EDGES]
    const int*   batch= (const int*)d_in[2];   // [N_NODES], sorted
    const float* W1a  = (const float*)d_in[3];
    const float* b1a  = (const float*)d_in[4];
    const float* W1b  = (const float*)d_in[5];
    const float* b1b  = (const float*)d_in[6];
    const float* W2a  = (const float*)d_in[7];
    const float* b2a  = (const float*)d_in[8];
    const float* W2b  = (const float*)d_in[9];
    const float* b2b  = (const float*)d_in[10];
    const float* Wfc  = (const float*)d_in[11];
    const float* bfc  = (const float*)d_in[12];
    float* out = (float*)d_out;

    // workspace layout (4-byte units), ~16.9 MB total
    float* ws     = (float*)d_ws;
    float* xw1    = ws;                                    // N_NODES*16
    float* h1w    = xw1 + (size_t)N_NODES * F1;            // N_NODES*8
    int*   srcs   = (int*)(h1w + (size_t)N_NODES * F2);    // N_EDGES
    int*   rowptr = srcs + N_EDGES;                        // N_NODES+1
    int*   bsum   = rowptr + (N_NODES + 1);                // 256 (NBLK used)
    int*   cnt    = bsum + 256;                            // N_NODES+1  (memset)
    float* gsum   = (float*)(cnt + (N_NODES + 1));         // NGRAPH*F2  (memset)
    float* gcnt   = gsum + NGRAPH * F2;                    // NGRAPH     (memset)

    // single memset: cnt + gsum + gcnt are adjacent
    hipMemsetAsync(cnt, 0,
                   ((size_t)(N_NODES + 1) + NGRAPH * F2 + NGRAPH) * sizeof(int),
                   stream);

    xform_hist_k<<<(N_EDGES + 255) / 256, 256, 0, stream>>>(x, W1a, xw1, ei, cnt);
    scanB_k<<<NBLK, SCAN_B, 0, stream>>>(cnt, rowptr, bsum);
    scanD_k<<<NBLK, SCAN_B, 0, stream>>>(rowptr, bsum);
    fill_k<<<(N_EDGES + 255) / 256, 256, 0, stream>>>(ei, rowptr, cnt, srcs);
    gin1_k<<<(N_NODES + 255) / 256, 256, 0, stream>>>(xw1, rowptr, srcs,
                                                      b1a, W1b, b1b, W2a, h1w);
    gin2pool_k<<<(N_NODES + 255) / 256, 256, 0, stream>>>(h1w, rowptr, srcs,
                                                          b2a, W2b, b2b, batch,
                                                          gsum, gcnt);
    final_k<<<1, 64, 0, stream>>>(gsum, gcnt, Wfc, bfc, out);
}